// Round 1
// baseline (564.363 us; speedup 1.0000x reference)
//
#include <hip/hip_runtime.h>

// ---------------------------------------------------------------------------
// InternalSequenceEmbedder: bidirectional diagonal linear SSM + MLP.
// B=32, T=8192, E=256, D=32, H=32, M=64.
//
// Pipeline:
//  k0_prep : fold Wpi@Win -> WuT (bf16, [64 ch][256 k]), biases, sigmoid(loga),
//            W1 transposes, W2@Wpo folds, combined output bias.
//  k1_proj : (BT x 256) @ (256 x 64) bf16 MFMA 16x16x32, u (bf16) to ws.
//  k2_scan : chunked scan (L=256) in LDS, fwd ch 0..31, bwd ch 32..63,
//            in-place u->h_local, writes per-chunk end states E.
//  k3_carry: cross-chunk carry scan (2048 independent series x 32 chunks).
//  k4_out  : h = h_local + carry*a^(k+1); y=h@Wout; out += y@Wpo + sum_j
//            gelu(y@W1)_j * (W2@Wpo)_j  (biases pre-folded). fp32 vector,
//            wave-uniform weight indices -> scalar loads.
// ---------------------------------------------------------------------------

typedef unsigned short u16;
typedef unsigned int   u32;
typedef __bf16 bf16x8 __attribute__((ext_vector_type(8)));
typedef float  f32x4  __attribute__((ext_vector_type(4)));

constexpr int BB = 32, TT = 8192, EE = 256, DD = 32, NCH = 64;
constexpr int BT = BB * TT;            // 262144 tokens
constexpr int LCH = 256;               // scan chunk length
constexpr int NCHUNK = TT / LCH;       // 32
constexpr int SUBLEN = 64;             // per-thread sub-chunk in k2

__device__ __forceinline__ u16 f2bf(float x) {
    union { float f; u32 u; } v; v.f = x;
    u32 r = (v.u + 0x7FFFu + ((v.u >> 16) & 1u)) >> 16;
    return (u16)r;
}
__device__ __forceinline__ float bf2f(u16 x) {
    union { u32 u; float f; } v; v.u = ((u32)x) << 16;
    return v.f;
}
__device__ __forceinline__ float gelu_tanh(float x) {
    // jax.nn.gelu default (approximate=True)
    float inner = 0.7978845608028654f * fmaf(0.044715f * x, x * x, x);
    float ez = __expf(2.f * inner);
    float t = 1.f - 2.f / (ez + 1.f);        // NaN-free tanh
    return 0.5f * x * (1.f + t);
}

// ---------------------------------------------------------------------------
__global__ void k0_prep(const float* __restrict__ Wpi, const float* __restrict__ bpi,
                        const float* __restrict__ fWin, const float* __restrict__ fbin,
                        const float* __restrict__ floga,
                        const float* __restrict__ bWin, const float* __restrict__ bbin,
                        const float* __restrict__ bloga,
                        const float* __restrict__ fW1, const float* __restrict__ bW1,
                        const float* __restrict__ fW2, const float* __restrict__ bW2,
                        const float* __restrict__ fb2, const float* __restrict__ bb2,
                        const float* __restrict__ Wpo, const float* __restrict__ bpo,
                        u16* __restrict__ WuT, float* __restrict__ bu,
                        float* __restrict__ a_arr, float* __restrict__ l2a,
                        float* __restrict__ fW1T, float* __restrict__ bW1T,
                        float* __restrict__ W2poF, float* __restrict__ W2poB,
                        float* __restrict__ bc)
{
    const int blk = blockIdx.x, tid = threadIdx.x;
    if (blk < 64) {                       // WuT row n = Wpi @ Win column n
        const float* Win = (blk < 32) ? fWin : bWin;
        const int nn = blk & 31;
        float s = 0.f;
        #pragma unroll
        for (int d = 0; d < 32; ++d) s = fmaf(Wpi[tid * 32 + d], Win[d * 32 + nn], s);
        WuT[blk * 256 + tid] = f2bf(s);
        if (tid == 0) {
            const float* bin = (blk < 32) ? fbin : bbin;
            float sb = bin[nn];
            for (int d = 0; d < 32; ++d) sb = fmaf(bpi[d], Win[d * 32 + nn], sb);
            bu[blk] = sb;
        }
    } else if (blk == 64) {
        if (tid < 64) {                   // decay + log2
            const float* lg = (tid < 32) ? floga : bloga;
            float a = 1.f / (1.f + __expf(-lg[tid & 31]));
            a_arr[tid] = a;
            l2a[tid] = log2f(a);
        } else if (tid < 96) {            // combined bias: bpo + fb2@WpoF + bb2@WpoB
            int i = tid - 64;
            float s = bpo[i];
            for (int d = 0; d < 32; ++d) s = fmaf(fb2[d], Wpo[d * 32 + i], s);
            for (int d = 0; d < 32; ++d) s = fmaf(bb2[d], Wpo[(32 + d) * 32 + i], s);
            bc[i] = s;
        }
    } else if (blk == 65 || blk == 66) {  // W1 transpose (column-major access fix)
        const float* W1 = (blk == 65) ? fW1 : bW1;
        float* W1T = (blk == 65) ? fW1T : bW1T;
        for (int x = tid; x < 2048; x += 256) {
            int j = x >> 5, i = x & 31;
            W1T[j * 32 + i] = W1[i * 64 + j];
        }
    } else {                              // W2 @ Wpo-block fold
        const float* W2 = (blk == 67) ? fW2 : bW2;
        const float* Wp = (blk == 67) ? Wpo : (Wpo + 32 * 32);
        float* Dst = (blk == 67) ? W2poF : W2poB;
        for (int x = tid; x < 2048; x += 256) {
            int j = x >> 5, i = x & 31;
            float s = 0.f;
            for (int d = 0; d < 32; ++d) s = fmaf(W2[j * 32 + d], Wp[d * 32 + i], s);
            Dst[j * 32 + i] = s;
        }
    }
}

// ---------------------------------------------------------------------------
// k1: u[token][ch] = bf16( e[token][:] @ Wu[:, ch] + bu[ch] )
// 64-token tile per block, 4 waves x (16 rows x 64 cols), K=256.
// A staged fp32->bf16 in LDS (pad +8 bf16); B frags read direct from global
// (32 KB, L2-resident) to stay under the 64 KB static-LDS limit.
__global__ __launch_bounds__(256) void k1_proj(const float* __restrict__ e,
                                               const u16* __restrict__ WuT,
                                               const float* __restrict__ bu,
                                               u16* __restrict__ u)
{
    __shared__ __align__(16) u16 As[64][264];
    const int tid = threadIdx.x;
    const size_t m0 = (size_t)blockIdx.x * 64;

    const float4* eg = reinterpret_cast<const float4*>(e + m0 * 256);
    #pragma unroll
    for (int it = 0; it < 16; ++it) {
        int i = tid + it * 256;           // 4096 float4 = 64 rows x 256 k
        int r = i >> 6, kk = (i & 63) << 2;
        float4 v = eg[i];
        uint2 pk;
        pk.x = (u32)f2bf(v.x) | ((u32)f2bf(v.y) << 16);
        pk.y = (u32)f2bf(v.z) | ((u32)f2bf(v.w) << 16);
        *reinterpret_cast<uint2*>(&As[r][kk]) = pk;
    }
    __syncthreads();

    const int lane = tid & 63, wave = tid >> 6;
    const int row16 = lane & 15, quad = lane >> 4;
    f32x4 acc[4] = {{0.f,0.f,0.f,0.f},{0.f,0.f,0.f,0.f},{0.f,0.f,0.f,0.f},{0.f,0.f,0.f,0.f}};

    #pragma unroll 2
    for (int ks = 0; ks < 8; ++ks) {
        bf16x8 av = *reinterpret_cast<const bf16x8*>(&As[wave * 16 + row16][ks * 32 + quad * 8]);
        #pragma unroll
        for (int ct = 0; ct < 4; ++ct) {
            bf16x8 bv = *reinterpret_cast<const bf16x8*>(WuT + (ct * 16 + row16) * 256 + ks * 32 + quad * 8);
            acc[ct] = __builtin_amdgcn_mfma_f32_16x16x32_bf16(av, bv, acc[ct], 0, 0, 0);
        }
    }
    // C/D layout: col = lane&15, row = quad*4 + reg  [m89/m91]
    #pragma unroll
    for (int ct = 0; ct < 4; ++ct) {
        int col = ct * 16 + row16;
        float bias = bu[col];
        #pragma unroll
        for (int r = 0; r < 4; ++r) {
            int row = wave * 16 + quad * 4 + r;
            u[(m0 + row) * 64 + col] = f2bf(acc[ct][r] + bias);
        }
    }
}

// ---------------------------------------------------------------------------
// k2: chunk-local scan, in place. block = (b, chunk); 64 ch x 4 sub-chunks.
__global__ __launch_bounds__(256) void k2_scan(u16* __restrict__ u,
                                               const float* __restrict__ a_arr,
                                               const float* __restrict__ l2a,
                                               float* __restrict__ Ebuf)
{
    __shared__ __align__(16) u16 tile[LCH * 64];
    __shared__ float eSub[64][4];
    const int tid = threadIdx.x;
    const int b = blockIdx.x >> 5, c = blockIdx.x & 31;
    const size_t base = (((size_t)b << 13) + ((size_t)c << 8)) * 64;

    const uint4* g = reinterpret_cast<const uint4*>(u + base);
    uint4* s4 = reinterpret_cast<uint4*>(tile);
    #pragma unroll
    for (int i = 0; i < 8; ++i) s4[tid + 256 * i] = g[tid + 256 * i];
    __syncthreads();

    const int ch = tid & 63, s = tid >> 6;
    const float a = a_arr[ch];
    const bool fwd = (ch < 32);

    float h = 0.f;
    if (fwd) {
        for (int i = 0; i < SUBLEN; ++i) {
            int t = s * SUBLEN + i;
            h = fmaf(a, h, bf2f(tile[t * 64 + ch]));
            tile[t * 64 + ch] = f2bf(h);
        }
    } else {
        for (int i = SUBLEN - 1; i >= 0; --i) {
            int t = s * SUBLEN + i;
            h = fmaf(a, h, bf2f(tile[t * 64 + ch]));
            tile[t * 64 + ch] = f2bf(h);
        }
    }
    eSub[ch][s] = h;
    __syncthreads();

    const float A = exp2f(64.f * l2a[ch]);       // a^SUBLEN
    float cin = 0.f;
    if (fwd) { for (int j = 0; j < s; ++j)      cin = fmaf(A, cin, eSub[ch][j]); }
    else     { for (int j = 3; j > s; --j)      cin = fmaf(A, cin, eSub[ch][j]); }

    if (fwd && s == 3)  Ebuf[(size_t)blockIdx.x * 64 + ch] = fmaf(A, cin, eSub[ch][3]);
    if (!fwd && s == 0) Ebuf[(size_t)blockIdx.x * 64 + ch] = fmaf(A, cin, eSub[ch][0]);

    float p = cin;
    if (fwd) {
        for (int i = 0; i < SUBLEN; ++i) {
            int t = s * SUBLEN + i; p *= a;
            tile[t * 64 + ch] = f2bf(bf2f(tile[t * 64 + ch]) + p);
        }
    } else {
        for (int i = SUBLEN - 1; i >= 0; --i) {
            int t = s * SUBLEN + i; p *= a;
            tile[t * 64 + ch] = f2bf(bf2f(tile[t * 64 + ch]) + p);
        }
    }
    __syncthreads();
    uint4* gw = reinterpret_cast<uint4*>(u + base);
    #pragma unroll
    for (int i = 0; i < 8; ++i) gw[tid + 256 * i] = s4[tid + 256 * i];
}

// ---------------------------------------------------------------------------
__global__ void k3_carry(const float* __restrict__ Ebuf, float* __restrict__ Cin,
                         const float* __restrict__ l2a)
{
    int tid = blockIdx.x * 256 + threadIdx.x;
    if (tid >= BB * NCH) return;
    int b = tid >> 6, ch = tid & 63;
    float aL = exp2f((float)LCH * l2a[ch]);      // a^256
    float S = 0.f;
    if (ch < 32) {
        for (int c = 0; c < NCHUNK; ++c) {
            size_t idx = ((size_t)(b * NCHUNK + c)) * 64 + ch;
            Cin[idx] = S; S = fmaf(aL, S, Ebuf[idx]);
        }
    } else {
        for (int c = NCHUNK - 1; c >= 0; --c) {
            size_t idx = ((size_t)(b * NCHUNK + c)) * 64 + ch;
            Cin[idx] = S; S = fmaf(aL, S, Ebuf[idx]);
        }
    }
}

// ---------------------------------------------------------------------------
// k4: one thread per token. Block = one (b, chunk) so carry index is uniform.
__global__ __launch_bounds__(256) void k4_out(const u16* __restrict__ h,
    const float* __restrict__ Cin, const float* __restrict__ l2a,
    const float* __restrict__ fWout, const float* __restrict__ fbout,
    const float* __restrict__ fW1T, const float* __restrict__ fb1,
    const float* __restrict__ bWout, const float* __restrict__ bbout,
    const float* __restrict__ bW1T, const float* __restrict__ bb1,
    const float* __restrict__ W2poF, const float* __restrict__ W2poB,
    const float* __restrict__ bc, const float* __restrict__ Wpo,
    float* __restrict__ out)
{
    const int tid = threadIdx.x;
    const int k = tid;                               // position in chunk (0..255)
    const size_t gt = (size_t)blockIdx.x * 256 + tid;
    const u16* hp = h + gt * 64;
    const float* cinp = Cin + (size_t)blockIdx.x * 64;   // uniform base per block

    float outacc[32];
    #pragma unroll
    for (int i = 0; i < 32; ++i) outacc[i] = bc[i];

    for (int dir = 0; dir < 2; ++dir) {
        const float* Wout = dir ? bWout : fWout;
        const float* bout = dir ? bbout : fbout;
        const float* W1T  = dir ? bW1T  : fW1T;
        const float* b1   = dir ? bb1   : fb1;
        const float* W2po = dir ? W2poB : W2poF;
        const int cb = dir ? 32 : 0;
        const float off = dir ? (float)(LCH - k) : (float)(k + 1);

        // y = h @ Wout + bout, with carry fix-up on h
        float yv[32];
        #pragma unroll
        for (int i = 0; i < 32; ++i) yv[i] = bout[i];
        for (int j0 = 0; j0 < 32; j0 += 8) {
            uint4 hv = *reinterpret_cast<const uint4*>(hp + cb + j0);
            u32 hw[4] = {hv.x, hv.y, hv.z, hv.w};
            #pragma unroll
            for (int jj = 0; jj < 8; ++jj) {
                const int j = j0 + jj;
                float hl = bf2f((u16)((hw[jj >> 1] >> ((jj & 1) * 16)) & 0xFFFFu));
                float hj = fmaf(cinp[cb + j], exp2f(off * l2a[cb + j]), hl);
                #pragma unroll
                for (int i = 0; i < 32; ++i) yv[i] = fmaf(hj, Wout[j * 32 + i], yv[i]);
            }
        }
        // out += y @ Wpo_block   (residual path through Wpo)
        #pragma unroll
        for (int j = 0; j < 32; ++j) {
            #pragma unroll
            for (int i = 0; i < 32; ++i)
                outacc[i] = fmaf(yv[j], Wpo[(cb + j) * 32 + i], outacc[i]);
        }
        // out += gelu(y@W1 + b1) @ (W2@Wpo_block)
        for (int j = 0; j < 64; ++j) {
            float z0 = b1[j], z1 = 0.f;
            #pragma unroll
            for (int i = 0; i < 16; ++i) z0 = fmaf(yv[i], W1T[j * 32 + i], z0);
            #pragma unroll
            for (int i = 16; i < 32; ++i) z1 = fmaf(yv[i], W1T[j * 32 + i], z1);
            float z = gelu_tanh(z0 + z1);
            #pragma unroll
            for (int i = 0; i < 32; ++i)
                outacc[i] = fmaf(z, W2po[j * 32 + i], outacc[i]);
        }
    }
    float4* op = reinterpret_cast<float4*>(out + gt * 32);
    #pragma unroll
    for (int q = 0; q < 8; ++q)
        op[q] = make_float4(outacc[4*q], outacc[4*q+1], outacc[4*q+2], outacc[4*q+3]);
}

// ---------------------------------------------------------------------------
extern "C" void kernel_launch(void* const* d_in, const int* in_sizes, int n_in,
                              void* d_out, int out_size, void* d_ws, size_t ws_size,
                              hipStream_t stream)
{
    (void)in_sizes; (void)n_in; (void)out_size; (void)ws_size;
    const float* e     = (const float*)d_in[0];
    const float* Wpi   = (const float*)d_in[1];
    const float* bpi   = (const float*)d_in[2];
    const float* Wpo   = (const float*)d_in[3];
    const float* bpo   = (const float*)d_in[4];
    const float* fWin  = (const float*)d_in[5];
    const float* fbin  = (const float*)d_in[6];
    const float* floga = (const float*)d_in[7];
    const float* fWout = (const float*)d_in[8];
    const float* fbout = (const float*)d_in[9];
    const float* fW1   = (const float*)d_in[10];
    const float* fb1   = (const float*)d_in[11];
    const float* fW2   = (const float*)d_in[12];
    const float* fb2   = (const float*)d_in[13];
    const float* bWin  = (const float*)d_in[14];
    const float* bbin  = (const float*)d_in[15];
    const float* bloga = (const float*)d_in[16];
    const float* bWout = (const float*)d_in[17];
    const float* bbout = (const float*)d_in[18];
    const float* bW1   = (const float*)d_in[19];
    const float* bb1   = (const float*)d_in[20];
    const float* bW2   = (const float*)d_in[21];
    const float* bb2   = (const float*)d_in[22];
    float* outp = (float*)d_out;

    char* ws = (char*)d_ws;
    size_t off = 0;
    auto walloc = [&](size_t bytes) { void* p = ws + off; off += (bytes + 255) & ~(size_t)255; return p; };
    u16*   u     = (u16*)  walloc((size_t)BT * 64 * 2);       // 32 MB: u then h_local (in place)
    u16*   WuT   = (u16*)  walloc(64 * 256 * 2);
    float* bu    = (float*)walloc(64 * 4);
    float* a_arr = (float*)walloc(64 * 4);
    float* l2a   = (float*)walloc(64 * 4);
    float* Ebuf  = (float*)walloc((size_t)BB * NCHUNK * 64 * 4);
    float* Cin   = (float*)walloc((size_t)BB * NCHUNK * 64 * 4);
    float* fW1T  = (float*)walloc(64 * 32 * 4);
    float* bW1T  = (float*)walloc(64 * 32 * 4);
    float* W2poF = (float*)walloc(64 * 32 * 4);
    float* W2poB = (float*)walloc(64 * 32 * 4);
    float* bc    = (float*)walloc(32 * 4);

    k0_prep<<<69, 256, 0, stream>>>(Wpi, bpi, fWin, fbin, floga, bWin, bbin, bloga,
                                    fW1, bW1, fW2, bW2, fb2, bb2, Wpo, bpo,
                                    WuT, bu, a_arr, l2a, fW1T, bW1T, W2poF, W2poB, bc);
    k1_proj<<<BT / 64, 256, 0, stream>>>(e, WuT, bu, u);
    k2_scan<<<BB * NCHUNK, 256, 0, stream>>>(u, a_arr, l2a, Ebuf);
    k3_carry<<<8, 256, 0, stream>>>(Ebuf, Cin, l2a);
    k4_out<<<BB * NCHUNK, 256, 0, stream>>>(u, Cin, l2a,
                                            fWout, fbout, fW1T, fb1,
                                            bWout, bbout, bW1T, bb1,
                                            W2poF, W2poB, bc, Wpo, outp);
}

// Round 2
// 463.430 us; speedup vs baseline: 1.2178x; 1.2178x over previous
//
#include <hip/hip_runtime.h>

// ---------------------------------------------------------------------------
// InternalSequenceEmbedder: bidirectional diagonal linear SSM + MLP.
// B=32, T=8192, E=256, D=32, H=32, M=64.
//
// Pipeline (round 2: fused + all-MFMA epilogue):
//  k0_prep : fold Wpi@Win -> WuT bf16 [64n][256k]; sigmoid/log2 decay; bf16
//            B-layout epilogue weights: WoutT[2][32n][32k], W1T[2][64n][32k],
//            WpoCatT[32n][64k], W2poCatT[32n][128k] (=W2@Wpo fold, dirs
//            stacked on K); combined bias bc = bpo + fb2@WpoF + bb2@WpoB.
//  kA      : per (b,chunk=256 tok): MFMA proj e@Wu -> u in LDS (8 sub-tiles
//            of 32 tok), then in-LDS chunked scan (k2 logic), write h_local
//            (bf16, coalesced) + per-chunk end states Ebuf. u never hits HBM.
//  k3_carry: cross-chunk carry scan (2048 series x 32 chunks).
//  kB      : all-MFMA epilogue. A-frags of h loaded from global with carry
//            fixup h += cin*a^(k+1) in regs; Y = Hfix@Wout + bout -> LDS
//            (bf16, XOR-swizzled, wave-private rows -> NO barrier);
//            OUT = Ycat@Wpo + gelu(Y@W1+b1)@(W2@Wpo) + bc, Z transposed
//            C->A via per-wave swizzled LDS scratch. fp32 accumulate.
// ---------------------------------------------------------------------------

typedef unsigned short u16;
typedef unsigned int   u32;
typedef __bf16 bf16x8 __attribute__((ext_vector_type(8)));
typedef float  f32x4  __attribute__((ext_vector_type(4)));

constexpr int BB = 32, TT = 8192, NCH = 64;
constexpr int BT = BB * TT;            // 262144 tokens
constexpr int LCH = 256;               // scan chunk length
constexpr int NCHUNK = TT / LCH;       // 32

#define MFMA16(av, bv, cc) __builtin_amdgcn_mfma_f32_16x16x32_bf16((av), (bv), (cc), 0, 0, 0)

__device__ __forceinline__ u16 f2bf(float x) {
    union { float f; u32 u; } v; v.f = x;
    u32 r = (v.u + 0x7FFFu + ((v.u >> 16) & 1u)) >> 16;
    return (u16)r;
}
__device__ __forceinline__ float bf2f(u16 x) {
    union { u32 u; float f; } v; v.u = ((u32)x) << 16;
    return v.f;
}
__device__ __forceinline__ float gelu_tanh(float x) {
    // jax.nn.gelu default (approximate=True)
    float inner = 0.7978845608028654f * fmaf(0.044715f * x, x * x, x);
    float ez = __expf(2.f * inner);
    float t = 1.f - 2.f / (ez + 1.f);        // NaN-free tanh
    return 0.5f * x * (1.f + t);
}

// ---------------------------------------------------------------------------
__global__ void k0_prep(const float* __restrict__ Wpi, const float* __restrict__ bpi,
                        const float* __restrict__ fWin, const float* __restrict__ fbin,
                        const float* __restrict__ floga,
                        const float* __restrict__ bWin, const float* __restrict__ bbin,
                        const float* __restrict__ bloga,
                        const float* __restrict__ fW1, const float* __restrict__ bW1,
                        const float* __restrict__ fW2, const float* __restrict__ bW2,
                        const float* __restrict__ fb2, const float* __restrict__ bb2,
                        const float* __restrict__ fWout, const float* __restrict__ bWout,
                        const float* __restrict__ Wpo, const float* __restrict__ bpo,
                        u16* __restrict__ WuT, float* __restrict__ bu,
                        float* __restrict__ a_arr, float* __restrict__ l2a,
                        u16* __restrict__ W1Tbf, u16* __restrict__ W2poCatT,
                        u16* __restrict__ WoutTbf, u16* __restrict__ WpoCatT,
                        float* __restrict__ bc)
{
    const int blk = blockIdx.x, tid = threadIdx.x;
    if (blk < 64) {                       // WuT row n = (Wpi @ Win) column n
        const float* Win = (blk < 32) ? fWin : bWin;
        const int nn = blk & 31;
        float s = 0.f;
        #pragma unroll
        for (int d = 0; d < 32; ++d) s = fmaf(Wpi[tid * 32 + d], Win[d * 32 + nn], s);
        WuT[blk * 256 + tid] = f2bf(s);
        if (tid == 0) {
            const float* bin = (blk < 32) ? fbin : bbin;
            float sb = bin[nn];
            for (int d = 0; d < 32; ++d) sb = fmaf(bpi[d], Win[d * 32 + nn], sb);
            bu[blk] = sb;
        }
    } else if (blk == 64) {
        if (tid < 64) {                   // decay + log2
            const float* lg = (tid < 32) ? floga : bloga;
            float a = 1.f / (1.f + __expf(-lg[tid & 31]));
            a_arr[tid] = a;
            l2a[tid] = log2f(a);
        } else if (tid < 96) {            // bc = bpo + fb2@WpoF + bb2@WpoB
            int i = tid - 64;
            float s = bpo[i];
            for (int d = 0; d < 32; ++d) s = fmaf(fb2[d], Wpo[d * 32 + i], s);
            for (int d = 0; d < 32; ++d) s = fmaf(bb2[d], Wpo[(32 + d) * 32 + i], s);
            bc[i] = s;
        }
    } else if (blk == 65 || blk == 66) {  // W1T bf16 [dir][64n][32k]
        int dir = blk - 65;
        const float* W1 = dir ? bW1 : fW1;
        for (int x = tid; x < 2048; x += 256) {
            int n = x >> 5, k = x & 31;
            W1Tbf[dir * 2048 + n * 32 + k] = f2bf(W1[k * 64 + n]);
        }
    } else if (blk == 67 || blk == 68) {  // W2@Wpo fold -> [32n][128k], k=dir*64+j
        int dir = blk - 67;
        const float* W2 = dir ? bW2 : fW2;
        const float* Wp = Wpo + dir * 32 * 32;
        for (int x = tid; x < 2048; x += 256) {
            int j = x >> 5, i = x & 31;
            float s = 0.f;
            for (int d = 0; d < 32; ++d) s = fmaf(W2[j * 32 + d], Wp[d * 32 + i], s);
            W2poCatT[i * 128 + dir * 64 + j] = f2bf(s);
        }
    } else if (blk == 69 || blk == 70) {  // WoutT bf16 [dir][32n][32k]
        int dir = blk - 69;
        const float* Wout = dir ? bWout : fWout;
        for (int x = tid; x < 1024; x += 256) {
            int n = x >> 5, k = x & 31;
            WoutTbf[dir * 1024 + n * 32 + k] = f2bf(Wout[k * 32 + n]);
        }
    } else {                              // WpoCatT bf16 [32n][64k]
        for (int x = tid; x < 2048; x += 256) {
            int n = x >> 6, k = x & 63;
            WpoCatT[n * 64 + k] = f2bf(Wpo[k * 32 + n]);
        }
    }
}

// ---------------------------------------------------------------------------
// kA: fused projection + chunk-local scan. Block = (b, chunk) = 256 tokens.
// LDS: As 32x264 u16 (staging) + utile 256x64 u16 (u/h tile) + eSub. ~50 KB.
__global__ __launch_bounds__(256) void kA_proj_scan(const float* __restrict__ e,
    const u16* __restrict__ WuT, const float* __restrict__ bu,
    const float* __restrict__ a_arr, const float* __restrict__ l2a,
    u16* __restrict__ h, float* __restrict__ Ebuf)
{
    __shared__ __align__(16) u16 As[32][264];
    __shared__ __align__(16) u16 utile[256 * 64];
    __shared__ float eSub[64][4];
    const int tid = threadIdx.x;
    const int blk = blockIdx.x;
    const size_t t0 = (size_t)blk * 256;
    const int lane = tid & 63, wave = tid >> 6;
    const int row16 = lane & 15, quad = lane >> 4;
    const int wr = (wave & 1) * 16;          // sub-tile row offset for this wave
    const int wc = (wave >> 1) * 32;         // col offset

    #pragma unroll 1
    for (int s = 0; s < 8; ++s) {            // 8 sub-tiles of 32 tokens
        const float4* eg = reinterpret_cast<const float4*>(e + (t0 + s * 32) * 256);
        #pragma unroll
        for (int it = 0; it < 8; ++it) {
            int i = tid + it * 256;          // 2048 float4 = 32 rows x 256 k
            int r = i >> 6, kk = (i & 63) << 2;
            float4 v = eg[i];
            uint2 pk;
            pk.x = (u32)f2bf(v.x) | ((u32)f2bf(v.y) << 16);
            pk.y = (u32)f2bf(v.z) | ((u32)f2bf(v.w) << 16);
            *reinterpret_cast<uint2*>(&As[r][kk]) = pk;
        }
        __syncthreads();
        f32x4 acc[2] = {{0.f,0.f,0.f,0.f},{0.f,0.f,0.f,0.f}};
        #pragma unroll
        for (int ks = 0; ks < 8; ++ks) {
            bf16x8 av = *reinterpret_cast<const bf16x8*>(&As[wr + row16][ks * 32 + quad * 8]);
            #pragma unroll
            for (int c2 = 0; c2 < 2; ++c2) {
                bf16x8 bv = *reinterpret_cast<const bf16x8*>(WuT + (wc + c2 * 16 + row16) * 256 + ks * 32 + quad * 8);
                acc[c2] = MFMA16(av, bv, acc[c2]);
            }
        }
        #pragma unroll
        for (int c2 = 0; c2 < 2; ++c2) {     // C/D: col=lane&15, row=quad*4+r
            int col = wc + c2 * 16 + row16;
            float bias = bu[col];
            #pragma unroll
            for (int r = 0; r < 4; ++r) {
                int trow = s * 32 + wr + quad * 4 + r;
                utile[trow * 64 + col] = f2bf(acc[c2][r] + bias);
            }
        }
        __syncthreads();
    }

    // ---- chunk-local scan on utile (64 ch x 4 sub-chunks of 64) ----
    const int ch = tid & 63, sid = tid >> 6;
    const float a = a_arr[ch];
    const bool fwd = (ch < 32);
    float hh = 0.f;
    if (fwd) {
        for (int i = 0; i < 64; ++i) { int t = sid * 64 + i;
            hh = fmaf(a, hh, bf2f(utile[t * 64 + ch])); utile[t * 64 + ch] = f2bf(hh); }
    } else {
        for (int i = 63; i >= 0; --i) { int t = sid * 64 + i;
            hh = fmaf(a, hh, bf2f(utile[t * 64 + ch])); utile[t * 64 + ch] = f2bf(hh); }
    }
    eSub[ch][sid] = hh;
    __syncthreads();
    const float A = exp2f(64.f * l2a[ch]);               // a^64
    float cin = 0.f;
    if (fwd) { for (int j = 0; j < sid; ++j) cin = fmaf(A, cin, eSub[ch][j]); }
    else     { for (int j = 3; j > sid; --j) cin = fmaf(A, cin, eSub[ch][j]); }
    if (fwd && sid == 3)  Ebuf[(size_t)blk * 64 + ch] = fmaf(A, cin, eSub[ch][3]);
    if (!fwd && sid == 0) Ebuf[(size_t)blk * 64 + ch] = fmaf(A, cin, eSub[ch][0]);
    float p = cin;
    if (fwd) {
        for (int i = 0; i < 64; ++i) { int t = sid * 64 + i; p *= a;
            utile[t * 64 + ch] = f2bf(bf2f(utile[t * 64 + ch]) + p); }
    } else {
        for (int i = 63; i >= 0; --i) { int t = sid * 64 + i; p *= a;
            utile[t * 64 + ch] = f2bf(bf2f(utile[t * 64 + ch]) + p); }
    }
    __syncthreads();
    uint4* gw = reinterpret_cast<uint4*>(h + t0 * 64);
    const uint4* s4 = reinterpret_cast<const uint4*>(utile);
    #pragma unroll
    for (int i = 0; i < 8; ++i) gw[tid + 256 * i] = s4[tid + 256 * i];
}

// ---------------------------------------------------------------------------
__global__ void k3_carry(const float* __restrict__ Ebuf, float* __restrict__ Cin,
                         const float* __restrict__ l2a)
{
    int tid = blockIdx.x * 256 + threadIdx.x;
    if (tid >= BB * NCH) return;
    int b = tid >> 6, ch = tid & 63;
    float aL = exp2f((float)LCH * l2a[ch]);      // a^256
    float S = 0.f;
    if (ch < 32) {
        for (int c = 0; c < NCHUNK; ++c) {
            size_t idx = ((size_t)(b * NCHUNK + c)) * 64 + ch;
            Cin[idx] = S; S = fmaf(aL, S, Ebuf[idx]);
        }
    } else {
        for (int c = NCHUNK - 1; c >= 0; --c) {
            size_t idx = ((size_t)(b * NCHUNK + c)) * 64 + ch;
            Cin[idx] = S; S = fmaf(aL, S, Ebuf[idx]);
        }
    }
}

// ---------------------------------------------------------------------------
// kB: all-MFMA epilogue. Block = (b, chunk) = 256 tokens; wave owns 64 rows.
// No __syncthreads needed: every LDS region is produced & consumed by the
// same wave. XOR swizzle (colblock ^ row&7) kills the 16-way column-read
// conflicts on the 128B-stride tiles.
__global__ __launch_bounds__(256) void kB_out(const u16* __restrict__ h,
    const float* __restrict__ Cin, const float* __restrict__ l2a,
    const u16* __restrict__ WoutTbf, const float* __restrict__ fbout, const float* __restrict__ bbout,
    const u16* __restrict__ W1Tbf, const float* __restrict__ fb1, const float* __restrict__ bb1,
    const u16* __restrict__ WpoCatT, const u16* __restrict__ W2poCatT,
    const float* __restrict__ bc, float* __restrict__ out)
{
    __shared__ __align__(16) u16 Yt[256 * 64];       // [token][dir*32+n], swizzled
    __shared__ __align__(16) u16 Zw[4][16 * 128];    // per-wave scratch, swizzled
    const int tid = threadIdx.x;
    const int blk = blockIdx.x;
    const size_t t0 = (size_t)blk * 256;
    const int lane = tid & 63, wave = tid >> 6;
    const int row16 = lane & 15, quad = lane >> 4;
    const float* cinp = Cin + (size_t)blk * 64;      // uniform per block

    // ---- phase 1: Y = (h + cin*a^off) @ Wout + bout  -> Yt ----
    #pragma unroll 1
    for (int rr = 0; rr < 4; ++rr) {
        const int rt = wave * 4 + rr;
        const int kpos = rt * 16 + row16;            // token pos in chunk (A row m)
        #pragma unroll
        for (int dir = 0; dir < 2; ++dir) {
            uint4 hv = *reinterpret_cast<const uint4*>(h + (t0 + kpos) * 64 + dir * 32 + quad * 8);
            u32 hw[4] = {hv.x, hv.y, hv.z, hv.w};
            const float off = dir ? (float)(LCH - kpos) : (float)(kpos + 1);
            union { bf16x8 v; u16 s[8]; } af;
            #pragma unroll
            for (int j = 0; j < 8; ++j) {
                int chn = dir * 32 + quad * 8 + j;
                float f = bf2f((u16)((hw[j >> 1] >> ((j & 1) * 16)) & 0xFFFFu));
                f = fmaf(cinp[chn], exp2f(off * l2a[chn]), f);
                af.s[j] = f2bf(f);
            }
            f32x4 yv[2] = {{0.f,0.f,0.f,0.f},{0.f,0.f,0.f,0.f}};
            #pragma unroll
            for (int nt = 0; nt < 2; ++nt) {
                bf16x8 bv = *reinterpret_cast<const bf16x8*>(WoutTbf + dir * 1024 + (nt * 16 + row16) * 32 + quad * 8);
                yv[nt] = MFMA16(af.v, bv, yv[nt]);
            }
            const float* boutp = dir ? bbout : fbout;
            #pragma unroll
            for (int nt = 0; nt < 2; ++nt) {
                float bb = boutp[nt * 16 + row16];
                #pragma unroll
                for (int r = 0; r < 4; ++r) {
                    int row = rt * 16 + quad * 4 + r;
                    int col = dir * 32 + nt * 16 + row16;
                    int cs = (col >> 3) ^ (row & 7);
                    Yt[row * 64 + cs * 8 + (col & 7)] = f2bf(yv[nt][r] + bb);
                }
            }
        }
    }

    // ---- phase 2: OUT = Ycat@Wpo + gelu(Y@W1+b1)@W2po + bc ----
    #pragma unroll 1
    for (int rr = 0; rr < 4; ++rr) {
        const int rt = wave * 4 + rr;
        const int arow = rt * 16 + row16;            // A row (token)
        f32x4 o0 = {0.f,0.f,0.f,0.f}, o1 = {0.f,0.f,0.f,0.f};

        // residual path: Ycat (K=64) @ WpoCat
        #pragma unroll
        for (int kb = 0; kb < 2; ++kb) {
            int cs = (kb * 4 + quad) ^ (arow & 7);
            bf16x8 av = *reinterpret_cast<const bf16x8*>(&Yt[arow * 64 + cs * 8]);
            bf16x8 bv0 = *reinterpret_cast<const bf16x8*>(WpoCatT + (row16) * 64 + kb * 32 + quad * 8);
            bf16x8 bv1 = *reinterpret_cast<const bf16x8*>(WpoCatT + (16 + row16) * 64 + kb * 32 + quad * 8);
            o0 = MFMA16(av, bv0, o0);
            o1 = MFMA16(av, bv1, o1);
        }
        // Z = gelu(Y_dir @ W1_dir + b1) -> Zw (per-wave, swizzled)
        #pragma unroll
        for (int dir = 0; dir < 2; ++dir) {
            int cs = (dir * 4 + quad) ^ (arow & 7);
            bf16x8 av = *reinterpret_cast<const bf16x8*>(&Yt[arow * 64 + cs * 8]);
            const float* b1p = dir ? bb1 : fb1;
            #pragma unroll
            for (int nt2 = 0; nt2 < 4; ++nt2) {
                f32x4 z = {0.f,0.f,0.f,0.f};
                bf16x8 bv = *reinterpret_cast<const bf16x8*>(W1Tbf + dir * 2048 + (nt2 * 16 + row16) * 32 + quad * 8);
                z = MFMA16(av, bv, z);
                float bb = b1p[nt2 * 16 + row16];
                #pragma unroll
                for (int r = 0; r < 4; ++r) {
                    float zz = gelu_tanh(z[r] + bb);
                    int zrow = quad * 4 + r;
                    int zcol = dir * 64 + nt2 * 16 + row16;
                    int zcs = (zcol >> 3) ^ (zrow & 7);
                    Zw[wave][zrow * 128 + zcs * 8 + (zcol & 7)] = f2bf(zz);
                }
            }
        }
        // MLP path: Zcat (K=128) @ W2poCat
        #pragma unroll
        for (int kb = 0; kb < 4; ++kb) {
            int zcs = (kb * 4 + quad) ^ (row16 & 7);
            bf16x8 av = *reinterpret_cast<const bf16x8*>(&Zw[wave][row16 * 128 + zcs * 8]);
            bf16x8 bv0 = *reinterpret_cast<const bf16x8*>(W2poCatT + (row16) * 128 + kb * 32 + quad * 8);
            bf16x8 bv1 = *reinterpret_cast<const bf16x8*>(W2poCatT + (16 + row16) * 128 + kb * 32 + quad * 8);
            o0 = MFMA16(av, bv0, o0);
            o1 = MFMA16(av, bv1, o1);
        }
        #pragma unroll
        for (int r = 0; r < 4; ++r) {
            size_t row = t0 + rt * 16 + quad * 4 + r;
            out[row * 32 + row16]      = o0[r] + bc[row16];
            out[row * 32 + 16 + row16] = o1[r] + bc[16 + row16];
        }
    }
}

// ---------------------------------------------------------------------------
extern "C" void kernel_launch(void* const* d_in, const int* in_sizes, int n_in,
                              void* d_out, int out_size, void* d_ws, size_t ws_size,
                              hipStream_t stream)
{
    (void)in_sizes; (void)n_in; (void)out_size; (void)ws_size;
    const float* e     = (const float*)d_in[0];
    const float* Wpi   = (const float*)d_in[1];
    const float* bpi   = (const float*)d_in[2];
    const float* Wpo   = (const float*)d_in[3];
    const float* bpo   = (const float*)d_in[4];
    const float* fWin  = (const float*)d_in[5];
    const float* fbin  = (const float*)d_in[6];
    const float* floga = (const float*)d_in[7];
    const float* fWout = (const float*)d_in[8];
    const float* fbout = (const float*)d_in[9];
    const float* fW1   = (const float*)d_in[10];
    const float* fb1   = (const float*)d_in[11];
    const float* fW2   = (const float*)d_in[12];
    const float* fb2   = (const float*)d_in[13];
    const float* bWin  = (const float*)d_in[14];
    const float* bbin  = (const float*)d_in[15];
    const float* bloga = (const float*)d_in[16];
    const float* bWout = (const float*)d_in[17];
    const float* bbout = (const float*)d_in[18];
    const float* bW1   = (const float*)d_in[19];
    const float* bb1   = (const float*)d_in[20];
    const float* bW2   = (const float*)d_in[21];
    const float* bb2   = (const float*)d_in[22];
    float* outp = (float*)d_out;

    char* ws = (char*)d_ws;
    size_t off = 0;
    auto walloc = [&](size_t bytes) { void* p = ws + off; off += (bytes + 255) & ~(size_t)255; return p; };
    u16*   hbuf  = (u16*)  walloc((size_t)BT * 64 * 2);       // 32 MB h_local
    u16*   WuT   = (u16*)  walloc(64 * 256 * 2);
    float* bu    = (float*)walloc(64 * 4);
    float* a_arr = (float*)walloc(64 * 4);
    float* l2a   = (float*)walloc(64 * 4);
    float* Ebuf  = (float*)walloc((size_t)BB * NCHUNK * 64 * 4);
    float* Cin   = (float*)walloc((size_t)BB * NCHUNK * 64 * 4);
    u16*   W1Tbf    = (u16*)walloc(2 * 64 * 32 * 2);
    u16*   W2poCatT = (u16*)walloc(32 * 128 * 2);
    u16*   WoutTbf  = (u16*)walloc(2 * 32 * 32 * 2);
    u16*   WpoCatT  = (u16*)walloc(32 * 64 * 2);
    float* bc    = (float*)walloc(32 * 4);

    k0_prep<<<72, 256, 0, stream>>>(Wpi, bpi, fWin, fbin, floga, bWin, bbin, bloga,
                                    fW1, bW1, fW2, bW2, fb2, bb2, fWout, bWout, Wpo, bpo,
                                    WuT, bu, a_arr, l2a, W1Tbf, W2poCatT, WoutTbf, WpoCatT, bc);
    kA_proj_scan<<<BB * NCHUNK, 256, 0, stream>>>(e, WuT, bu, a_arr, l2a, hbuf, Ebuf);
    k3_carry<<<8, 256, 0, stream>>>(Ebuf, Cin, l2a);
    kB_out<<<BB * NCHUNK, 256, 0, stream>>>(hbuf, Cin, l2a,
                                            WoutTbf, fbout, bbout,
                                            W1Tbf, fb1, bb1,
                                            WpoCatT, W2poCatT, bc, outp);
}